// Round 5
// baseline (643.840 us; speedup 1.0000x reference)
//
#include <hip/hip_runtime.h>

#define HW 4096
#define CCH 256
#define IC 128

typedef __bf16 bf16x8 __attribute__((ext_vector_type(8)));
typedef float f32x4 __attribute__((ext_vector_type(4)));

#define MFMA16(a, b, c) __builtin_amdgcn_mfma_f32_16x16x32_bf16(a, b, c, 0, 0, 0)

static __device__ __forceinline__ float4 ld4(const float* p) {
  return *reinterpret_cast<const float4*>(p);
}
static __device__ __forceinline__ void st4(float* p, float4 v) {
  *reinterpret_cast<float4*>(p) = v;
}
static __device__ __forceinline__ unsigned int pack_bf16(float a, float b) {
  union { __bf16 h; unsigned short u; } ua, ub;
  ua.h = (__bf16)a; ub.h = (__bf16)b;
  return ((unsigned int)ub.u << 16) | (unsigned int)ua.u;
}
static __device__ __forceinline__ bf16x8 ldb8(const __bf16* p) {
  return *reinterpret_cast<const bf16x8*>(p);
}

// ---------------------------------------------------------------------------
// theta projection (pixel-major bf16) + xB emission (x transposed, bf16 [px][256])
__global__ __launch_bounds__(256) void k_projT(const float* __restrict__ in,
                                               const float* __restrict__ w,
                                               const float* __restrict__ bias,
                                               __bf16* __restrict__ out,
                                               __bf16* __restrict__ xB) {
  const int n = blockIdx.y;
  const int p0 = blockIdx.x * 64;
  const float* inN = in + (size_t)n * CCH * HW;
  __shared__ float sIn[16][68];
  __shared__ float sW[16][132];
  const int tid = threadIdx.x;
  const int tp = tid & 15, to = tid >> 4;
  const int px = tid & 63, cp = tid >> 6;
  float acc[4][8];
#pragma unroll
  for (int i = 0; i < 4; ++i)
#pragma unroll
    for (int j = 0; j < 8; ++j) acc[i][j] = 0.f;

  for (int c0 = 0; c0 < CCH; c0 += 16) {
    __syncthreads();
    {
      int cc = tid >> 4, p4 = tid & 15;
      st4(&sIn[cc][p4 * 4], ld4(&inN[(size_t)(c0 + cc) * HW + p0 + p4 * 4]));
    }
#pragma unroll
    for (int i = 0; i < 2; ++i) {
      int e4 = tid + 256 * i;
      int o = e4 >> 2, c4 = e4 & 3;
      float4 wv = ld4(&w[(size_t)o * CCH + c0 + c4 * 4]);
      sW[c4 * 4 + 0][o] = wv.x;
      sW[c4 * 4 + 1][o] = wv.y;
      sW[c4 * 4 + 2][o] = wv.z;
      sW[c4 * 4 + 3][o] = wv.w;
    }
    __syncthreads();
    {
      unsigned int* xr = (unsigned int*)(xB + ((size_t)n * HW + p0 + px) * 256 + c0);
#pragma unroll
      for (int i = 0; i < 2; ++i) {
        int ch2 = 2 * (cp + 4 * i);
        xr[cp + 4 * i] = pack_bf16(sIn[ch2][px], sIn[ch2 + 1][px]);
      }
    }
#pragma unroll
    for (int kk = 0; kk < 16; ++kk) {
      float4 bv = ld4(&sIn[kk][tp * 4]);
      float4 a0 = ld4(&sW[kk][to * 8]);
      float4 a1 = ld4(&sW[kk][to * 8 + 4]);
      float bb[4] = {bv.x, bv.y, bv.z, bv.w};
      float aa[8] = {a0.x, a0.y, a0.z, a0.w, a1.x, a1.y, a1.z, a1.w};
#pragma unroll
      for (int i = 0; i < 4; ++i)
#pragma unroll
        for (int j = 0; j < 8; ++j) acc[i][j] = fmaf(bb[i], aa[j], acc[i][j]);
    }
  }
  float bs[8];
#pragma unroll
  for (int j = 0; j < 8; ++j) bs[j] = bias[to * 8 + j];
  __bf16* dst = out + ((size_t)n * HW + p0) * IC;
#pragma unroll
  for (int i = 0; i < 4; ++i) {
    bf16x8 v;
#pragma unroll
    for (int j = 0; j < 8; ++j) v[j] = (__bf16)(acc[i][j] + bs[j]);
    *reinterpret_cast<bf16x8*>(&dst[(size_t)(tp * 4 + i) * IC + to * 8]) = v;
  }
}

// ---------------------------------------------------------------------------
// phi (pixel-major) + g (channel-major) projections, one pass over x_ref
__global__ __launch_bounds__(256) void k_projPG(const float* __restrict__ in,
                                                const float* __restrict__ wPhi,
                                                const float* __restrict__ wG,
                                                const float* __restrict__ bPhi,
                                                const float* __restrict__ bG,
                                                __bf16* __restrict__ phB,
                                                __bf16* __restrict__ gB) {
  const int n = blockIdx.y;
  const int p0 = blockIdx.x * 64;
  const float* inN = in + (size_t)n * CCH * HW;
  __shared__ float sIn[16][68];
  __shared__ float sW[16][264];
  __shared__ __attribute__((aligned(16))) __bf16 sT[128][72];
  const int tid = threadIdx.x;
  const int tp = tid & 15, to = tid >> 4;
  float acc[4][16];
#pragma unroll
  for (int i = 0; i < 4; ++i)
#pragma unroll
    for (int j = 0; j < 16; ++j) acc[i][j] = 0.f;

  for (int c0 = 0; c0 < CCH; c0 += 16) {
    __syncthreads();
    {
      int cc = tid >> 4, p4 = tid & 15;
      st4(&sIn[cc][p4 * 4], ld4(&inN[(size_t)(c0 + cc) * HW + p0 + p4 * 4]));
    }
#pragma unroll
    for (int i = 0; i < 4; ++i) {
      int e4 = tid + 256 * i;
      int o = e4 >> 2, c4 = e4 & 3;
      const float* wsrc = (o < 128) ? &wPhi[(size_t)o * CCH + c0 + c4 * 4]
                                    : &wG[(size_t)(o - 128) * CCH + c0 + c4 * 4];
      float4 wv = ld4(wsrc);
      sW[c4 * 4 + 0][o] = wv.x;
      sW[c4 * 4 + 1][o] = wv.y;
      sW[c4 * 4 + 2][o] = wv.z;
      sW[c4 * 4 + 3][o] = wv.w;
    }
    __syncthreads();
#pragma unroll
    for (int kk = 0; kk < 16; ++kk) {
      float4 bv = ld4(&sIn[kk][tp * 4]);
      float bb[4] = {bv.x, bv.y, bv.z, bv.w};
      float aa[16];
      float4 a0 = ld4(&sW[kk][to * 16 + 0]);
      float4 a1 = ld4(&sW[kk][to * 16 + 4]);
      float4 a2 = ld4(&sW[kk][to * 16 + 8]);
      float4 a3 = ld4(&sW[kk][to * 16 + 12]);
      aa[0]=a0.x; aa[1]=a0.y; aa[2]=a0.z; aa[3]=a0.w;
      aa[4]=a1.x; aa[5]=a1.y; aa[6]=a1.z; aa[7]=a1.w;
      aa[8]=a2.x; aa[9]=a2.y; aa[10]=a2.z; aa[11]=a2.w;
      aa[12]=a3.x; aa[13]=a3.y; aa[14]=a3.z; aa[15]=a3.w;
#pragma unroll
      for (int i = 0; i < 4; ++i)
#pragma unroll
        for (int j = 0; j < 16; ++j) acc[i][j] = fmaf(bb[i], aa[j], acc[i][j]);
    }
  }
  float bs[16];
#pragma unroll
  for (int j = 0; j < 16; ++j) {
    int o = to * 16 + j;
    bs[j] = (o < 128) ? bPhi[o] : bG[o - 128];
  }
  if (to < 8) {
    __bf16* dst = phB + ((size_t)n * HW + p0) * IC;
#pragma unroll
    for (int i = 0; i < 4; ++i) {
      bf16x8 v0, v1;
#pragma unroll
      for (int j = 0; j < 8; ++j) {
        v0[j] = (__bf16)(acc[i][j] + bs[j]);
        v1[j] = (__bf16)(acc[i][8 + j] + bs[8 + j]);
      }
      *reinterpret_cast<bf16x8*>(&dst[(size_t)(tp * 4 + i) * IC + to * 16]) = v0;
      *reinterpret_cast<bf16x8*>(&dst[(size_t)(tp * 4 + i) * IC + to * 16 + 8]) = v1;
    }
  }
  __syncthreads();
  if (to >= 8) {
#pragma unroll
    for (int i = 0; i < 4; ++i)
#pragma unroll
      for (int j = 0; j < 16; ++j)
        sT[(to - 8) * 16 + j][tp * 4 + i] = (__bf16)(acc[i][j] + bs[j]);
  }
  __syncthreads();
  const int row = tid >> 1, half = tid & 1;
  __bf16* dst = gB + (size_t)n * IC * HW + (size_t)row * HW + p0 + half * 32;
#pragma unroll
  for (int m = 0; m < 4; ++m)
    *reinterpret_cast<bf16x8*>(&dst[m * 8]) =
        *reinterpret_cast<const bf16x8*>(&sT[row][half * 32 + m * 8]);
}

// ---------------------------------------------------------------------------
// prep: W2 = c1y@out_w (bf16), bias2 = c1_b + c1y@out_b, cast c1x & out_w to bf16
__global__ __launch_bounds__(256) void k_prep(const float* __restrict__ c1_w,
                                              const float* __restrict__ c1_b,
                                              const float* __restrict__ out_w,
                                              const float* __restrict__ out_b,
                                              __bf16* __restrict__ c1xB,
                                              __bf16* __restrict__ W2B,
                                              __bf16* __restrict__ outwB,
                                              float* __restrict__ bias2) {
  const int bx = blockIdx.x, tid = threadIdx.x;
  if (bx < 256) {
    const int o = bx;
    c1xB[(size_t)o * 256 + tid] = (__bf16)c1_w[(size_t)o * 512 + tid];
    if (tid < 128) {
      float s = 0.f;
      for (int c = 0; c < 256; ++c)
        s = fmaf(c1_w[(size_t)o * 512 + 256 + c], out_w[(size_t)c * 128 + tid], s);
      W2B[(size_t)o * 128 + tid] = (__bf16)s;
    } else if (tid == 128) {
      float s = 0.f;
      for (int c = 0; c < 256; ++c)
        s = fmaf(c1_w[(size_t)o * 512 + 256 + c], out_b[c], s);
      bias2[o] = c1_b[o] + s;
    }
  } else {
    const int o = bx - 256;
    if (tid < 128) outwB[(size_t)o * 128 + tid] = (__bf16)out_w[(size_t)o * 128 + tid];
  }
}

// ---------------------------------------------------------------------------
// attnA: partial rowsums. grid (64 qb, 4 kq, 4 n) x 256 thr (4 waves).
// wave = 16 q rows x 1024 k. No LDS staging, no k-loop barriers.
__global__ __launch_bounds__(256, 4) void k_attnA(const __bf16* __restrict__ thB,
                                                  const __bf16* __restrict__ phB,
                                                  float* __restrict__ partRS) {
  const int qb = blockIdx.x;
  const int kq = blockIdx.y;
  const int n = blockIdx.z;
  const int tid = threadIdx.x;
  const int qg = tid >> 6;
  const int lane = tid & 63;
  const int l15 = lane & 15, lg = lane >> 4;
  const int q0 = qb * 64 + qg * 16;

  const __bf16* phN = phB + (size_t)n * HW * IC;
  const float scale = 0.08838834764831845f;

  const __bf16* thRow = thB + ((size_t)n * HW + q0 + l15) * IC + lg * 8;
  bf16x8 aQ[4];
#pragma unroll
  for (int cj = 0; cj < 4; ++cj) aQ[cj] = ldb8(thRow + 32 * cj);

  float rs[4] = {0.f, 0.f, 0.f, 0.f};
  for (int it = 0; it < 16; ++it) {
    const int k0 = kq * 1024 + it * 64;
    f32x4 cc[4] = {{0, 0, 0, 0}, {0, 0, 0, 0}, {0, 0, 0, 0}, {0, 0, 0, 0}};
#pragma unroll
    for (int kt = 0; kt < 4; ++kt)
#pragma unroll
      for (int cj = 0; cj < 4; ++cj) {
        bf16x8 b = ldb8(&phN[(size_t)(k0 + kt * 16 + l15) * IC + cj * 32 + lg * 8]);
        cc[kt] = MFMA16(aQ[cj], b, cc[kt]);
      }
#pragma unroll
    for (int kt = 0; kt < 4; ++kt)
#pragma unroll
      for (int r = 0; r < 4; ++r) rs[r] += __expf(cc[kt][r] * scale);
  }
#pragma unroll
  for (int m = 1; m < 16; m <<= 1)
#pragma unroll
    for (int r = 0; r < 4; ++r) rs[r] += __shfl_xor(rs[r], m, 64);
  if (l15 == 0) {
#pragma unroll
    for (int r = 0; r < 4; ++r)
      partRS[((size_t)n * 4 + kq) * HW + q0 + lg * 4 + r] = rs[r];
  }
}

// ---------------------------------------------------------------------------
// attnB: QK recompute + normalize + coalesced P store + PV partial.
// grid (64 qb, 2 kh, 4 n) x 512 thr = 8 waves (qg 0..3, ks 0..1).
// wave = 16 q x 1024 k. No phi/g LDS staging.
union BShm {
  float pf[8][16][68];
  float y[64][132];
};
__global__ __launch_bounds__(512, 4) void k_attnB(const __bf16* __restrict__ thB,
                                                  const __bf16* __restrict__ phB,
                                                  const __bf16* __restrict__ gB,
                                                  const float* __restrict__ partRS,
                                                  float* __restrict__ P,
                                                  float* __restrict__ yTpart) {
  const int qb = blockIdx.x;
  const int kh = blockIdx.y;
  const int n = blockIdx.z;
  const int tid = threadIdx.x;
  const int wv = tid >> 6;
  const int lane = tid & 63;
  const int qg = wv & 3;
  const int ks = wv >> 2;
  const int l15 = lane & 15, lg = lane >> 4;
  const int q0 = qb * 64 + qg * 16;

  __shared__ BShm sU;
  __shared__ __attribute__((aligned(16))) __bf16 sPb[8][16][72];
  __shared__ float sInv[64];

  const __bf16* phN = phB + (size_t)n * HW * IC;
  const __bf16* gN = gB + (size_t)n * IC * HW;
  const float scale = 0.08838834764831845f;

  if (tid < 64) {
    const int q = qb * 64 + tid;
    float s = partRS[((size_t)n * 4 + 0) * HW + q] + partRS[((size_t)n * 4 + 1) * HW + q] +
              partRS[((size_t)n * 4 + 2) * HW + q] + partRS[((size_t)n * 4 + 3) * HW + q];
    sInv[tid] = 1.f / s;
  }
  __syncthreads();
  float inv4[4];
#pragma unroll
  for (int r = 0; r < 4; ++r) inv4[r] = sInv[qg * 16 + lg * 4 + r];

  const __bf16* thRow = thB + ((size_t)n * HW + q0 + l15) * IC + lg * 8;
  bf16x8 aQ[4];
#pragma unroll
  for (int cj = 0; cj < 4; ++cj) aQ[cj] = ldb8(thRow + 32 * cj);

  f32x4 accY[8];
#pragma unroll
  for (int t = 0; t < 8; ++t) accY[t] = (f32x4){0, 0, 0, 0};

  const int kbase = kh * 2048 + ks * 1024;
  for (int it = 0; it < 16; ++it) {
    const int k0 = kbase + it * 64;
    f32x4 cc[4] = {{0, 0, 0, 0}, {0, 0, 0, 0}, {0, 0, 0, 0}, {0, 0, 0, 0}};
#pragma unroll
    for (int kt = 0; kt < 4; ++kt)
#pragma unroll
      for (int cj = 0; cj < 4; ++cj) {
        bf16x8 b = ldb8(&phN[(size_t)(k0 + kt * 16 + l15) * IC + cj * 32 + lg * 8]);
        cc[kt] = MFMA16(aQ[cj], b, cc[kt]);
      }
#pragma unroll
    for (int kt = 0; kt < 4; ++kt)
#pragma unroll
      for (int r = 0; r < 4; ++r) {
        float p = __expf(cc[kt][r] * scale) * inv4[r];
        sU.pf[wv][lg * 4 + r][kt * 16 + l15] = p;
        sPb[wv][lg * 4 + r][kt * 16 + l15] = (__bf16)p;
      }
    // coalesced P store: 4 x dwordx4, each row = 256 B contiguous
#pragma unroll
    for (int s = 0; s < 4; ++s) {
      const int row = s * 4 + lg;
      float4 v = ld4(&sU.pf[wv][row][l15 * 4]);
      st4(&P[((size_t)n * HW + q0 + row) * HW + k0 + l15 * 4], v);
    }
    // PV with normalized bf16 P (wave-private LDS, no barrier)
    bf16x8 aP0 = ldb8(&sPb[wv][l15][lg * 8]);
    bf16x8 aP1 = ldb8(&sPb[wv][l15][lg * 8 + 32]);
#pragma unroll
    for (int t = 0; t < 8; ++t) {
      bf16x8 b0 = ldb8(&gN[(size_t)(t * 16 + l15) * HW + k0 + lg * 8]);
      bf16x8 b1 = ldb8(&gN[(size_t)(t * 16 + l15) * HW + k0 + 32 + lg * 8]);
      accY[t] = MFMA16(aP0, b0, accY[t]);
      accY[t] = MFMA16(aP1, b1, accY[t]);
    }
  }

  // combine the two ks sub-halves within the block, write yT partial (per kh)
  __syncthreads();
  if (ks == 0) {
#pragma unroll
    for (int t = 0; t < 8; ++t)
#pragma unroll
      for (int r = 0; r < 4; ++r)
        sU.y[qg * 16 + lg * 4 + r][t * 16 + l15] = accY[t][r];
  }
  __syncthreads();
  if (ks == 1) {
    float* dst = yTpart + (((size_t)n * 2 + kh) * HW + q0) * IC;
#pragma unroll
    for (int t = 0; t < 8; ++t)
#pragma unroll
      for (int r = 0; r < 4; ++r)
        dst[(size_t)(lg * 4 + r) * IC + t * 16 + l15] =
            accY[t][r] + sU.y[qg * 16 + lg * 4 + r][t * 16 + l15];
  }
}

// ---------------------------------------------------------------------------
// yred: yTB = bf16(yTpart[kh=0] + yTpart[kh=1]). grid (256, 4) x 256 thr.
__global__ __launch_bounds__(256) void k_yred(const float* __restrict__ yTpart,
                                              __bf16* __restrict__ yTB) {
  const int n = blockIdx.y;
  const size_t e = ((size_t)blockIdx.x * 256 + threadIdx.x) * 8;
  const float* p0 = yTpart + ((size_t)n * 2 + 0) * HW * IC + e;
  const float* p1 = yTpart + ((size_t)n * 2 + 1) * HW * IC + e;
  float4 a0 = ld4(p0), a1 = ld4(p0 + 4);
  float4 b0 = ld4(p1), b1 = ld4(p1 + 4);
  bf16x8 v;
  v[0] = (__bf16)(a0.x + b0.x); v[1] = (__bf16)(a0.y + b0.y);
  v[2] = (__bf16)(a0.z + b0.z); v[3] = (__bf16)(a0.w + b0.w);
  v[4] = (__bf16)(a1.x + b1.x); v[5] = (__bf16)(a1.y + b1.y);
  v[6] = (__bf16)(a1.z + b1.z); v[7] = (__bf16)(a1.w + b1.w);
  *reinterpret_cast<bf16x8*>(&yTB[(size_t)n * HW * IC + e]) = v;
}

// ---------------------------------------------------------------------------
// out conv via MFMA (LDS-free): y2b = outwB@yTB + out_b (bf16 channel-major)
__global__ __launch_bounds__(256) void k_outm(const __bf16* __restrict__ yTB,
                                              const __bf16* __restrict__ outwB,
                                              const float* __restrict__ outb,
                                              __bf16* __restrict__ y2b) {
  const int n = blockIdx.y;
  const int px0 = blockIdx.x * 64;
  const int tid = threadIdx.x;
  const int w = tid >> 6, lane = tid & 63;
  const int l15 = lane & 15, lg = lane >> 4;
  const int o0 = w * 64;
  f32x4 acc[4][4];
#pragma unroll
  for (int i = 0; i < 4; ++i)
#pragma unroll
    for (int j = 0; j < 4; ++j) acc[i][j] = (f32x4){0, 0, 0, 0};

  const __bf16* yRow = yTB + ((size_t)n * HW + px0) * 128;
#pragma unroll
  for (int s = 0; s < 4; ++s) {
    bf16x8 a[4], b[4];
#pragma unroll
    for (int t = 0; t < 4; ++t) {
      a[t] = ldb8(&outwB[(size_t)(o0 + t * 16 + l15) * 128 + s * 32 + lg * 8]);
      b[t] = ldb8(&yRow[(size_t)(t * 16 + l15) * 128 + s * 32 + lg * 8]);
    }
#pragma unroll
    for (int i = 0; i < 4; ++i)
#pragma unroll
      for (int j = 0; j < 4; ++j) acc[i][j] = MFMA16(a[i], b[j], acc[i][j]);
  }
#pragma unroll
  for (int i = 0; i < 4; ++i)
#pragma unroll
    for (int r = 0; r < 4; ++r) {
      int o = o0 + i * 16 + lg * 4 + r;
      float bb = outb[o];
      __bf16* dst = y2b + ((size_t)n * CCH + o) * HW + px0;
#pragma unroll
      for (int j = 0; j < 4; ++j)
        dst[j * 16 + l15] = (__bf16)(acc[i][j][r] + bb);
    }
}

// ---------------------------------------------------------------------------
// c1 via MFMA (LDS-free): coef1 = relu(c1xB@xB + W2B@yTB + bias2), bf16 out
__global__ __launch_bounds__(256) void k_c1m(const __bf16* __restrict__ xB,
                                             const __bf16* __restrict__ yTB,
                                             const __bf16* __restrict__ c1xB,
                                             const __bf16* __restrict__ W2B,
                                             const float* __restrict__ bias2,
                                             __bf16* __restrict__ coef1) {
  const int n = blockIdx.y;
  const int px0 = blockIdx.x * 64;
  const int tid = threadIdx.x;
  const int w = tid >> 6, lane = tid & 63;
  const int l15 = lane & 15, lg = lane >> 4;
  const int o0 = w * 64;
  f32x4 acc[4][4];
#pragma unroll
  for (int i = 0; i < 4; ++i)
#pragma unroll
    for (int j = 0; j < 4; ++j) acc[i][j] = (f32x4){0, 0, 0, 0};

  const __bf16* xRow = xB + ((size_t)n * HW + px0) * 256;
  const __bf16* yRow = yTB + ((size_t)n * HW + px0) * 128;

#pragma unroll
  for (int s = 0; s < 8; ++s) {
    bf16x8 a[4], b[4];
#pragma unroll
    for (int t = 0; t < 4; ++t) {
      a[t] = ldb8(&c1xB[(size_t)(o0 + t * 16 + l15) * 256 + s * 32 + lg * 8]);
      b[t] = ldb8(&xRow[(size_t)(t * 16 + l15) * 256 + s * 32 + lg * 8]);
    }
#pragma unroll
    for (int i = 0; i < 4; ++i)
#pragma unroll
      for (int j = 0; j < 4; ++j) acc[i][j] = MFMA16(a[i], b[j], acc[i][j]);
  }
#pragma unroll
  for (int s = 0; s < 4; ++s) {
    bf16x8 a[4], b[4];
#pragma unroll
    for (int t = 0; t < 4; ++t) {
      a[t] = ldb8(&W2B[(size_t)(o0 + t * 16 + l15) * 128 + s * 32 + lg * 8]);
      b[t] = ldb8(&yRow[(size_t)(t * 16 + l15) * 128 + s * 32 + lg * 8]);
    }
#pragma unroll
    for (int i = 0; i < 4; ++i)
#pragma unroll
      for (int j = 0; j < 4; ++j) acc[i][j] = MFMA16(a[i], b[j], acc[i][j]);
  }
#pragma unroll
  for (int i = 0; i < 4; ++i)
#pragma unroll
    for (int r = 0; r < 4; ++r) {
      int o = o0 + i * 16 + lg * 4 + r;
      float bb = bias2[o];
      __bf16* dst = coef1 + ((size_t)n * CCH + o) * HW + px0;
#pragma unroll
      for (int j = 0; j < 4; ++j)
        dst[j * 16 + l15] = (__bf16)fmaxf(acc[i][j][r] + bb, 0.f);
    }
}

// ---------------------------------------------------------------------------
__global__ __launch_bounds__(256) void k_c2p(const __bf16* __restrict__ coef1,
                                             const float* __restrict__ w,
                                             float* __restrict__ part) {
  const int n = blockIdx.y;
  const int kc = blockIdx.z;
  const int p = blockIdx.x * 256 + threadIdx.x;
  const int px = p & 63, py = p >> 6;
  float acc[16];
#pragma unroll
  for (int o = 0; o < 16; ++o) acc[o] = 0.f;
  const __bf16* base = coef1 + (size_t)n * CCH * HW + (size_t)kc * 64 * HW;
  for (int c = 0; c < 64; ++c) {
    const __bf16* img = base + (size_t)c * HW;
    float v[9];
#pragma unroll
    for (int dy = -1; dy <= 1; ++dy)
#pragma unroll
      for (int dx = -1; dx <= 1; ++dx) {
        int yy = py + dy, xx = px + dx;
        bool ok = ((unsigned)yy < 64u) && ((unsigned)xx < 64u);
        v[(dy + 1) * 3 + dx + 1] = ok ? (float)img[yy * 64 + xx] : 0.f;
      }
    const int cg = kc * 64 + c;
#pragma unroll
    for (int o = 0; o < 16; ++o) {
      const float* wp = w + ((size_t)o * CCH + cg) * 9;
      float a = acc[o];
      a = fmaf(wp[0], v[0], a); a = fmaf(wp[1], v[1], a); a = fmaf(wp[2], v[2], a);
      a = fmaf(wp[3], v[3], a); a = fmaf(wp[4], v[4], a); a = fmaf(wp[5], v[5], a);
      a = fmaf(wp[6], v[6], a); a = fmaf(wp[7], v[7], a); a = fmaf(wp[8], v[8], a);
      acc[o] = a;
    }
  }
  float* dst = part + (((size_t)kc * 4 + n) * 16) * HW + p;
#pragma unroll
  for (int o = 0; o < 16; ++o) dst[(size_t)o * HW] = acc[o];
}

__global__ __launch_bounds__(256) void k_c2r(const float* __restrict__ part,
                                             const float* __restrict__ bias,
                                             float* __restrict__ c2o) {
  const int n = blockIdx.y;
  const int p = blockIdx.x * 256 + threadIdx.x;
#pragma unroll
  for (int o = 0; o < 16; ++o) {
    float s = bias[o];
#pragma unroll
    for (int kc = 0; kc < 4; ++kc)
      s += part[(((size_t)kc * 4 + n) * 16 + o) * HW + p];
    c2o[((size_t)n * 16 + o) * HW + p] = fmaxf(s, 0.f);
  }
}

// ---------------------------------------------------------------------------
__global__ __launch_bounds__(256) void k_c3(const float* __restrict__ c2o,
                                            const float* __restrict__ w,
                                            const float* __restrict__ bias,
                                            float* __restrict__ c3o) {
  const int n = blockIdx.y;
  const int p = blockIdx.x * 256 + threadIdx.x;
  const int px = p & 63, py = p >> 6;
  float acc[3] = {bias[0], bias[1], bias[2]};
  for (int c = 0; c < 16; ++c) {
    const float* img = c2o + ((size_t)n * 16 + c) * HW;
    float v[9];
#pragma unroll
    for (int dy = -1; dy <= 1; ++dy)
#pragma unroll
      for (int dx = -1; dx <= 1; ++dx) {
        int yy = py + dy, xx = px + dx;
        bool ok = ((unsigned)yy < 64u) && ((unsigned)xx < 64u);
        v[(dy + 1) * 3 + dx + 1] = ok ? img[yy * 64 + xx] : 0.f;
      }
#pragma unroll
    for (int o = 0; o < 3; ++o) {
      const float* wp = w + ((size_t)o * 16 + c) * 9;
      float a = acc[o];
      a = fmaf(wp[0], v[0], a); a = fmaf(wp[1], v[1], a); a = fmaf(wp[2], v[2], a);
      a = fmaf(wp[3], v[3], a); a = fmaf(wp[4], v[4], a); a = fmaf(wp[5], v[5], a);
      a = fmaf(wp[6], v[6], a); a = fmaf(wp[7], v[7], a); a = fmaf(wp[8], v[8], a);
      acc[o] = a;
    }
  }
#pragma unroll
  for (int o = 0; o < 3; ++o)
    c3o[((size_t)n * 3 + o) * HW + p] = fmaxf(acc[o], 0.f);
}

// ---------------------------------------------------------------------------
__global__ __launch_bounds__(256) void k_c4f(const float* __restrict__ c3o,
                                             const float* __restrict__ w4,
                                             const float* __restrict__ b4,
                                             const float* __restrict__ x,
                                             const __bf16* __restrict__ y2b,
                                             float* __restrict__ out0) {
  const int n = blockIdx.y;
  const int cc = blockIdx.z;
  const int p = blockIdx.x * 256 + threadIdx.x;
  const int px = p & 63, py = p >> 6;
  float coef = b4[0];
#pragma unroll
  for (int c = 0; c < 3; ++c) {
    const float* img = c3o + ((size_t)n * 3 + c) * HW;
#pragma unroll
    for (int dy = -1; dy <= 1; ++dy)
#pragma unroll
      for (int dx = -1; dx <= 1; ++dx) {
        int yy = py + dy, xx = px + dx;
        bool ok = ((unsigned)yy < 64u) && ((unsigned)xx < 64u);
        float v = ok ? img[yy * 64 + xx] : 0.f;
        coef = fmaf(w4[c * 9 + (dy + 1) * 3 + dx + 1], v, coef);
      }
  }
  const size_t base = ((size_t)n * CCH + cc * 64) * HW + p;
#pragma unroll 8
  for (int c = 0; c < 64; ++c) {
    size_t a = base + (size_t)c * HW;
    out0[a] = x[a] + coef * (float)y2b[a];
  }
}

// ---------------------------------------------------------------------------
extern "C" void kernel_launch(void* const* d_in, const int* in_sizes, int n_in,
                              void* d_out, int out_size, void* d_ws, size_t ws_size,
                              hipStream_t stream) {
  (void)in_sizes; (void)n_in; (void)out_size; (void)ws_size;
  const float* x     = (const float*)d_in[0];
  const float* x_ref = (const float*)d_in[1];
  const float* g_w   = (const float*)d_in[2];
  const float* g_b   = (const float*)d_in[3];
  const float* th_w  = (const float*)d_in[4];
  const float* th_b  = (const float*)d_in[5];
  const float* ph_w  = (const float*)d_in[6];
  const float* ph_b  = (const float*)d_in[7];
  const float* out_w = (const float*)d_in[8];
  const float* out_b = (const float*)d_in[9];
  const float* c1_w  = (const float*)d_in[10];
  const float* c1_b  = (const float*)d_in[11];
  const float* c2_w  = (const float*)d_in[12];
  const float* c2_b  = (const float*)d_in[13];
  const float* c3_w  = (const float*)d_in[14];
  const float* c3_b  = (const float*)d_in[15];
  const float* c4_w  = (const float*)d_in[16];
  const float* c4_b  = (const float*)d_in[17];

  float* ws = (float*)d_ws;
  __bf16* xB     = (__bf16*)(ws + 0);
  __bf16* yTB    = (__bf16*)(ws + 2097152);
  __bf16* thB    = (__bf16*)(ws + 3145728);
  __bf16* phB    = (__bf16*)(ws + 4194304);
  __bf16* gBf    = (__bf16*)(ws + 5242880);
  __bf16* coef1B = (__bf16*)(ws + 3145728);  // aliases thB+phB (dead after attnB)
  __bf16* y2b    = (__bf16*)(ws + 6291456);
  float* c2p     = ws + 8388608;
  float* c2o     = ws + 9437184;
  float* c3o     = ws + 9699328;
  __bf16* c1xB   = (__bf16*)(ws + 9748480);
  __bf16* W2B    = (__bf16*)(ws + 9781248);
  __bf16* outwB  = (__bf16*)(ws + 9797632);
  float* bias2   = ws + 9814016;
  float* partRS  = ws + 9814272;             // 65536 floats
  float* yTpart  = ws + 9879808;             // 4.19M floats

  float* out0 = (float*)d_out;
  float* P    = out0 + 4194304;

  dim3 blk(256);
  k_projT<<<dim3(64, 4), blk, 0, stream>>>(x, th_w, th_b, thB, xB);
  k_projPG<<<dim3(64, 4), blk, 0, stream>>>(x_ref, ph_w, g_w, ph_b, g_b, phB, gBf);
  k_prep<<<dim3(512), blk, 0, stream>>>(c1_w, c1_b, out_w, out_b, c1xB, W2B, outwB, bias2);
  k_attnA<<<dim3(64, 4, 4), blk, 0, stream>>>(thB, phB, partRS);
  k_attnB<<<dim3(64, 2, 4), dim3(512), 0, stream>>>(thB, phB, gBf, partRS, P, yTpart);
  k_yred<<<dim3(256, 4), blk, 0, stream>>>(yTpart, yTB);
  k_outm<<<dim3(64, 4), blk, 0, stream>>>(yTB, outwB, out_b, y2b);
  k_c1m<<<dim3(64, 4), blk, 0, stream>>>(xB, yTB, c1xB, W2B, bias2, coef1B);
  k_c2p<<<dim3(16, 4, 4), blk, 0, stream>>>(coef1B, c2_w, c2p);
  k_c2r<<<dim3(16, 4), blk, 0, stream>>>(c2p, c2_b, c2o);
  k_c3<<<dim3(16, 4), blk, 0, stream>>>(c2o, c3_w, c3_b, c3o);
  k_c4f<<<dim3(16, 4, 4), blk, 0, stream>>>(c3o, c4_w, c4_b, x, y2b, out0);
}

// Round 10
// 410.401 us; speedup vs baseline: 1.5688x; 1.5688x over previous
//
#include <hip/hip_runtime.h>

#define HW 4096
#define CCH 256
#define IC 128

typedef __bf16 bf16x8 __attribute__((ext_vector_type(8)));
typedef float f32x4 __attribute__((ext_vector_type(4)));

#define MFMA16(a, b, c) __builtin_amdgcn_mfma_f32_16x16x32_bf16(a, b, c, 0, 0, 0)

static __device__ __forceinline__ float4 ld4(const float* p) {
  return *reinterpret_cast<const float4*>(p);
}
static __device__ __forceinline__ void st4(float* p, float4 v) {
  *reinterpret_cast<float4*>(p) = v;
}
static __device__ __forceinline__ unsigned int pack_bf16(float a, float b) {
  union { __bf16 h; unsigned short u; } ua, ub;
  ua.h = (__bf16)a; ub.h = (__bf16)b;
  return ((unsigned int)ub.u << 16) | (unsigned int)ua.u;
}
static __device__ __forceinline__ bf16x8 ldb8(const __bf16* p) {
  return *reinterpret_cast<const bf16x8*>(p);
}

// ---------------------------------------------------------------------------
// theta projection (pixel-major bf16) + xB emission (x transposed, bf16 [px][256])
__global__ __launch_bounds__(256) void k_projT(const float* __restrict__ in,
                                               const float* __restrict__ w,
                                               const float* __restrict__ bias,
                                               __bf16* __restrict__ out,
                                               __bf16* __restrict__ xB) {
  const int n = blockIdx.y;
  const int p0 = blockIdx.x * 64;
  const float* inN = in + (size_t)n * CCH * HW;
  __shared__ float sIn[16][68];
  __shared__ float sW[16][132];
  const int tid = threadIdx.x;
  const int tp = tid & 15, to = tid >> 4;
  const int px = tid & 63, cp = tid >> 6;
  float acc[4][8];
#pragma unroll
  for (int i = 0; i < 4; ++i)
#pragma unroll
    for (int j = 0; j < 8; ++j) acc[i][j] = 0.f;

  for (int c0 = 0; c0 < CCH; c0 += 16) {
    __syncthreads();
    {
      int cc = tid >> 4, p4 = tid & 15;
      st4(&sIn[cc][p4 * 4], ld4(&inN[(size_t)(c0 + cc) * HW + p0 + p4 * 4]));
    }
#pragma unroll
    for (int i = 0; i < 2; ++i) {
      int e4 = tid + 256 * i;
      int o = e4 >> 2, c4 = e4 & 3;
      float4 wv = ld4(&w[(size_t)o * CCH + c0 + c4 * 4]);
      sW[c4 * 4 + 0][o] = wv.x;
      sW[c4 * 4 + 1][o] = wv.y;
      sW[c4 * 4 + 2][o] = wv.z;
      sW[c4 * 4 + 3][o] = wv.w;
    }
    __syncthreads();
    {
      unsigned int* xr = (unsigned int*)(xB + ((size_t)n * HW + p0 + px) * 256 + c0);
#pragma unroll
      for (int i = 0; i < 2; ++i) {
        int ch2 = 2 * (cp + 4 * i);
        xr[cp + 4 * i] = pack_bf16(sIn[ch2][px], sIn[ch2 + 1][px]);
      }
    }
#pragma unroll
    for (int kk = 0; kk < 16; ++kk) {
      float4 bv = ld4(&sIn[kk][tp * 4]);
      float4 a0 = ld4(&sW[kk][to * 8]);
      float4 a1 = ld4(&sW[kk][to * 8 + 4]);
      float bb[4] = {bv.x, bv.y, bv.z, bv.w};
      float aa[8] = {a0.x, a0.y, a0.z, a0.w, a1.x, a1.y, a1.z, a1.w};
#pragma unroll
      for (int i = 0; i < 4; ++i)
#pragma unroll
        for (int j = 0; j < 8; ++j) acc[i][j] = fmaf(bb[i], aa[j], acc[i][j]);
    }
  }
  float bs[8];
#pragma unroll
  for (int j = 0; j < 8; ++j) bs[j] = bias[to * 8 + j];
  __bf16* dst = out + ((size_t)n * HW + p0) * IC;
#pragma unroll
  for (int i = 0; i < 4; ++i) {
    bf16x8 v;
#pragma unroll
    for (int j = 0; j < 8; ++j) v[j] = (__bf16)(acc[i][j] + bs[j]);
    *reinterpret_cast<bf16x8*>(&dst[(size_t)(tp * 4 + i) * IC + to * 8]) = v;
  }
}

// ---------------------------------------------------------------------------
// phi (pixel-major) + g (k-tiled channel-major [kblk][128][64]) projections
__global__ __launch_bounds__(256) void k_projPG(const float* __restrict__ in,
                                                const float* __restrict__ wPhi,
                                                const float* __restrict__ wG,
                                                const float* __restrict__ bPhi,
                                                const float* __restrict__ bG,
                                                __bf16* __restrict__ phB,
                                                __bf16* __restrict__ gB2) {
  const int n = blockIdx.y;
  const int p0 = blockIdx.x * 64;
  const float* inN = in + (size_t)n * CCH * HW;
  __shared__ float sIn[16][68];
  __shared__ float sW[16][264];
  __shared__ __attribute__((aligned(16))) __bf16 sT[128][72];
  const int tid = threadIdx.x;
  const int tp = tid & 15, to = tid >> 4;
  float acc[4][16];
#pragma unroll
  for (int i = 0; i < 4; ++i)
#pragma unroll
    for (int j = 0; j < 16; ++j) acc[i][j] = 0.f;

  for (int c0 = 0; c0 < CCH; c0 += 16) {
    __syncthreads();
    {
      int cc = tid >> 4, p4 = tid & 15;
      st4(&sIn[cc][p4 * 4], ld4(&inN[(size_t)(c0 + cc) * HW + p0 + p4 * 4]));
    }
#pragma unroll
    for (int i = 0; i < 4; ++i) {
      int e4 = tid + 256 * i;
      int o = e4 >> 2, c4 = e4 & 3;
      const float* wsrc = (o < 128) ? &wPhi[(size_t)o * CCH + c0 + c4 * 4]
                                    : &wG[(size_t)(o - 128) * CCH + c0 + c4 * 4];
      float4 wv = ld4(wsrc);
      sW[c4 * 4 + 0][o] = wv.x;
      sW[c4 * 4 + 1][o] = wv.y;
      sW[c4 * 4 + 2][o] = wv.z;
      sW[c4 * 4 + 3][o] = wv.w;
    }
    __syncthreads();
#pragma unroll
    for (int kk = 0; kk < 16; ++kk) {
      float4 bv = ld4(&sIn[kk][tp * 4]);
      float bb[4] = {bv.x, bv.y, bv.z, bv.w};
      float aa[16];
      float4 a0 = ld4(&sW[kk][to * 16 + 0]);
      float4 a1 = ld4(&sW[kk][to * 16 + 4]);
      float4 a2 = ld4(&sW[kk][to * 16 + 8]);
      float4 a3 = ld4(&sW[kk][to * 16 + 12]);
      aa[0]=a0.x; aa[1]=a0.y; aa[2]=a0.z; aa[3]=a0.w;
      aa[4]=a1.x; aa[5]=a1.y; aa[6]=a1.z; aa[7]=a1.w;
      aa[8]=a2.x; aa[9]=a2.y; aa[10]=a2.z; aa[11]=a2.w;
      aa[12]=a3.x; aa[13]=a3.y; aa[14]=a3.z; aa[15]=a3.w;
#pragma unroll
      for (int i = 0; i < 4; ++i)
#pragma unroll
        for (int j = 0; j < 16; ++j) acc[i][j] = fmaf(bb[i], aa[j], acc[i][j]);
    }
  }
  float bs[16];
#pragma unroll
  for (int j = 0; j < 16; ++j) {
    int o = to * 16 + j;
    bs[j] = (o < 128) ? bPhi[o] : bG[o - 128];
  }
  if (to < 8) {
    __bf16* dst = phB + ((size_t)n * HW + p0) * IC;
#pragma unroll
    for (int i = 0; i < 4; ++i) {
      bf16x8 v0, v1;
#pragma unroll
      for (int j = 0; j < 8; ++j) {
        v0[j] = (__bf16)(acc[i][j] + bs[j]);
        v1[j] = (__bf16)(acc[i][8 + j] + bs[8 + j]);
      }
      *reinterpret_cast<bf16x8*>(&dst[(size_t)(tp * 4 + i) * IC + to * 16]) = v0;
      *reinterpret_cast<bf16x8*>(&dst[(size_t)(tp * 4 + i) * IC + to * 16 + 8]) = v1;
    }
  }
  __syncthreads();
  if (to >= 8) {
#pragma unroll
    for (int i = 0; i < 4; ++i)
#pragma unroll
      for (int j = 0; j < 16; ++j)
        sT[(to - 8) * 16 + j][tp * 4 + i] = (__bf16)(acc[i][j] + bs[j]);
  }
  __syncthreads();
  // g: k-tiled layout gB2[n][kblk=p0/64][ic][64]
  const int row = tid >> 1, half = tid & 1;
  __bf16* dst = gB2 + ((size_t)(n * 64 + (p0 >> 6)) * 128 + row) * 64 + half * 32;
#pragma unroll
  for (int m = 0; m < 4; ++m)
    *reinterpret_cast<bf16x8*>(&dst[m * 8]) =
        *reinterpret_cast<const bf16x8*>(&sT[row][half * 32 + m * 8]);
}

// ---------------------------------------------------------------------------
// prep: W2 = c1y@out_w (bf16), bias2 = c1_b + c1y@out_b, cast c1x & out_w to bf16
__global__ __launch_bounds__(256) void k_prep(const float* __restrict__ c1_w,
                                              const float* __restrict__ c1_b,
                                              const float* __restrict__ out_w,
                                              const float* __restrict__ out_b,
                                              __bf16* __restrict__ c1xB,
                                              __bf16* __restrict__ W2B,
                                              __bf16* __restrict__ outwB,
                                              float* __restrict__ bias2) {
  const int bx = blockIdx.x, tid = threadIdx.x;
  if (bx < 256) {
    const int o = bx;
    c1xB[(size_t)o * 256 + tid] = (__bf16)c1_w[(size_t)o * 512 + tid];
    if (tid < 128) {
      float s = 0.f;
      for (int c = 0; c < 256; ++c)
        s = fmaf(c1_w[(size_t)o * 512 + 256 + c], out_w[(size_t)c * 128 + tid], s);
      W2B[(size_t)o * 128 + tid] = (__bf16)s;
    } else if (tid == 128) {
      float s = 0.f;
      for (int c = 0; c < 256; ++c)
        s = fmaf(c1_w[(size_t)o * 512 + 256 + c], out_b[c], s);
      bias2[o] = c1_b[o] + s;
    }
  } else {
    const int o = bx - 256;
    if (tid < 128) outwB[(size_t)o * 128 + tid] = (__bf16)out_w[(size_t)o * 128 + tid];
  }
}

// ---------------------------------------------------------------------------
// attnA: partial rowsums with LDS-staged phi. grid (64 qb, 4 kq, 4 n) x 256 thr.
__global__ __launch_bounds__(256, 4) void k_attnA(const __bf16* __restrict__ thB,
                                                  const __bf16* __restrict__ phB,
                                                  float* __restrict__ partRS) {
  const int qb = blockIdx.x, kq = blockIdx.y, n = blockIdx.z;
  const int tid = threadIdx.x;
  const int qg = tid >> 6, lane = tid & 63;
  const int l15 = lane & 15, lg = lane >> 4;
  const int q0 = qb * 64 + qg * 16;
  __shared__ __attribute__((aligned(16))) __bf16 sPhi[64][136];

  const __bf16* phN = phB + (size_t)n * HW * IC;
  const float scale = 0.08838834764831845f;

  const __bf16* thRow = thB + ((size_t)n * HW + q0 + l15) * IC + lg * 8;
  bf16x8 aQ[4];
#pragma unroll
  for (int cj = 0; cj < 4; ++cj) aQ[cj] = ldb8(thRow + 32 * cj);

  float rs[4] = {0.f, 0.f, 0.f, 0.f};
  for (int it = 0; it < 16; ++it) {
    const int k0 = kq * 1024 + it * 64;
    __syncthreads();
#pragma unroll
    for (int rep = 0; rep < 4; ++rep) {
      int row = (tid >> 4) + rep * 16, seg = tid & 15;
      *reinterpret_cast<bf16x8*>(&sPhi[row][seg * 8]) =
          ldb8(&phN[(size_t)(k0 + row) * IC + seg * 8]);
    }
    __syncthreads();
    f32x4 cc[4] = {{0, 0, 0, 0}, {0, 0, 0, 0}, {0, 0, 0, 0}, {0, 0, 0, 0}};
#pragma unroll
    for (int kt = 0; kt < 4; ++kt)
#pragma unroll
      for (int cj = 0; cj < 4; ++cj) {
        bf16x8 b = ldb8(&sPhi[kt * 16 + l15][cj * 32 + lg * 8]);
        cc[kt] = MFMA16(aQ[cj], b, cc[kt]);
      }
#pragma unroll
    for (int kt = 0; kt < 4; ++kt)
#pragma unroll
      for (int r = 0; r < 4; ++r) rs[r] += __expf(cc[kt][r] * scale);
  }
#pragma unroll
  for (int m = 1; m < 16; m <<= 1)
#pragma unroll
    for (int r = 0; r < 4; ++r) rs[r] += __shfl_xor(rs[r], m, 64);
  if (l15 == 0) {
#pragma unroll
    for (int r = 0; r < 4; ++r)
      partRS[((size_t)n * 4 + kq) * HW + q0 + lg * 4 + r] = rs[r];
  }
}

// ---------------------------------------------------------------------------
// attnB: QK recompute + normalize + P store + PV partial, all LDS-staged.
// grid (64 qb, 4 kq, 4 n) x 256 thr = 4 waves (qg). LDS 45.3 KB -> 3 blocks/CU.
__global__ __launch_bounds__(256, 3) void k_attnB(const __bf16* __restrict__ thB,
                                                  const __bf16* __restrict__ phB,
                                                  const __bf16* __restrict__ gB2,
                                                  const float* __restrict__ partRS,
                                                  float* __restrict__ P,
                                                  float* __restrict__ yTpart) {
  const int qb = blockIdx.x, kq = blockIdx.y, n = blockIdx.z;
  const int tid = threadIdx.x;
  const int qg = tid >> 6, lane = tid & 63;
  const int l15 = lane & 15, lg = lane >> 4;
  const int q0 = qb * 64 + qg * 16;

  __shared__ __attribute__((aligned(16))) __bf16 sPhi[64][136];
  __shared__ __attribute__((aligned(16))) __bf16 sG[128][72];
  __shared__ __attribute__((aligned(16))) __bf16 sPb[4][16][72];
  __shared__ float sInv[64];

  const __bf16* phN = phB + (size_t)n * HW * IC;
  const float scale = 0.08838834764831845f;

  if (tid < 64) {
    const int q = qb * 64 + tid;
    float s = partRS[((size_t)n * 4 + 0) * HW + q] + partRS[((size_t)n * 4 + 1) * HW + q] +
              partRS[((size_t)n * 4 + 2) * HW + q] + partRS[((size_t)n * 4 + 3) * HW + q];
    sInv[tid] = 1.f / s;
  }
  __syncthreads();
  float inv4[4];
#pragma unroll
  for (int r = 0; r < 4; ++r) inv4[r] = sInv[qg * 16 + lg * 4 + r];

  const __bf16* thRow = thB + ((size_t)n * HW + q0 + l15) * IC + lg * 8;
  bf16x8 aQ[4];
#pragma unroll
  for (int cj = 0; cj < 4; ++cj) aQ[cj] = ldb8(thRow + 32 * cj);

  f32x4 accY[8];
#pragma unroll
  for (int t = 0; t < 8; ++t) accY[t] = (f32x4){0, 0, 0, 0};

  // q0 already includes qg*16 — row offset below must use lg*4+r ONLY.
  float* PnW = P + ((size_t)n * HW + q0) * HW;

  for (int it = 0; it < 16; ++it) {
    const int k0 = kq * 1024 + it * 64;
    __syncthreads();
#pragma unroll
    for (int rep = 0; rep < 4; ++rep) {
      int row = (tid >> 4) + rep * 16, seg = tid & 15;
      *reinterpret_cast<bf16x8*>(&sPhi[row][seg * 8]) =
          ldb8(&phN[(size_t)(k0 + row) * IC + seg * 8]);
    }
    {
      const __bf16* gsrc = gB2 + (size_t)(n * 64 + (k0 >> 6)) * 128 * 64;
#pragma unroll
      for (int j = 0; j < 4; ++j)
        *reinterpret_cast<bf16x8*>(&sG[tid >> 1][(tid & 1) * 32 + j * 8]) =
            ldb8(&gsrc[(size_t)tid * 32 + j * 8]);
    }
    __syncthreads();
    f32x4 cc[4] = {{0, 0, 0, 0}, {0, 0, 0, 0}, {0, 0, 0, 0}, {0, 0, 0, 0}};
#pragma unroll
    for (int kt = 0; kt < 4; ++kt)
#pragma unroll
      for (int cj = 0; cj < 4; ++cj) {
        bf16x8 b = ldb8(&sPhi[kt * 16 + l15][cj * 32 + lg * 8]);
        cc[kt] = MFMA16(aQ[cj], b, cc[kt]);
      }
#pragma unroll
    for (int kt = 0; kt < 4; ++kt)
#pragma unroll
      for (int r = 0; r < 4; ++r) {
        float p = __expf(cc[kt][r] * scale) * inv4[r];
        PnW[(size_t)(lg * 4 + r) * HW + (k0 + kt * 16 + l15)] = p;
        sPb[qg][lg * 4 + r][kt * 16 + l15] = (__bf16)p;
      }
    // PV (wave-private sPb, no barrier needed)
    bf16x8 aP0 = ldb8(&sPb[qg][l15][lg * 8]);
    bf16x8 aP1 = ldb8(&sPb[qg][l15][lg * 8 + 32]);
#pragma unroll
    for (int t = 0; t < 8; ++t) {
      bf16x8 b0 = ldb8(&sG[t * 16 + l15][lg * 8]);
      bf16x8 b1 = ldb8(&sG[t * 16 + l15][lg * 8 + 32]);
      accY[t] = MFMA16(aP0, b0, accY[t]);
      accY[t] = MFMA16(aP1, b1, accY[t]);
    }
  }

  float* dst = yTpart + (((size_t)n * 4 + kq) * HW + q0) * IC;
#pragma unroll
  for (int t = 0; t < 8; ++t)
#pragma unroll
    for (int r = 0; r < 4; ++r)
      dst[(size_t)(lg * 4 + r) * IC + t * 16 + l15] = accY[t][r];
}

// ---------------------------------------------------------------------------
// yred: yTB = bf16(sum of 4 kq partials). grid (256, 4) x 256 thr.
__global__ __launch_bounds__(256) void k_yred(const float* __restrict__ yTpart,
                                              __bf16* __restrict__ yTB) {
  const int n = blockIdx.y;
  const size_t e = ((size_t)blockIdx.x * 256 + threadIdx.x) * 8;
  const size_t pstride = (size_t)HW * IC;
  const float* p0 = yTpart + ((size_t)n * 4 + 0) * pstride + e;
  const float* p1 = yTpart + ((size_t)n * 4 + 1) * pstride + e;
  const float* p2 = yTpart + ((size_t)n * 4 + 2) * pstride + e;
  const float* p3 = yTpart + ((size_t)n * 4 + 3) * pstride + e;
  float4 a0 = ld4(p0), a1 = ld4(p0 + 4);
  float4 b0 = ld4(p1), b1 = ld4(p1 + 4);
  float4 c0 = ld4(p2), c1 = ld4(p2 + 4);
  float4 d0 = ld4(p3), d1 = ld4(p3 + 4);
  bf16x8 v;
  v[0] = (__bf16)(a0.x + b0.x + c0.x + d0.x);
  v[1] = (__bf16)(a0.y + b0.y + c0.y + d0.y);
  v[2] = (__bf16)(a0.z + b0.z + c0.z + d0.z);
  v[3] = (__bf16)(a0.w + b0.w + c0.w + d0.w);
  v[4] = (__bf16)(a1.x + b1.x + c1.x + d1.x);
  v[5] = (__bf16)(a1.y + b1.y + c1.y + d1.y);
  v[6] = (__bf16)(a1.z + b1.z + c1.z + d1.z);
  v[7] = (__bf16)(a1.w + b1.w + c1.w + d1.w);
  *reinterpret_cast<bf16x8*>(&yTB[(size_t)n * pstride + e]) = v;
}

// ---------------------------------------------------------------------------
// out conv via MFMA (LDS-free): y2b = outwB@yTB + out_b (bf16 channel-major)
__global__ __launch_bounds__(256) void k_outm(const __bf16* __restrict__ yTB,
                                              const __bf16* __restrict__ outwB,
                                              const float* __restrict__ outb,
                                              __bf16* __restrict__ y2b) {
  const int n = blockIdx.y;
  const int px0 = blockIdx.x * 64;
  const int tid = threadIdx.x;
  const int w = tid >> 6, lane = tid & 63;
  const int l15 = lane & 15, lg = lane >> 4;
  const int o0 = w * 64;
  f32x4 acc[4][4];
#pragma unroll
  for (int i = 0; i < 4; ++i)
#pragma unroll
    for (int j = 0; j < 4; ++j) acc[i][j] = (f32x4){0, 0, 0, 0};

  const __bf16* yRow = yTB + ((size_t)n * HW + px0) * 128;
#pragma unroll
  for (int s = 0; s < 4; ++s) {
    bf16x8 a[4], b[4];
#pragma unroll
    for (int t = 0; t < 4; ++t) {
      a[t] = ldb8(&outwB[(size_t)(o0 + t * 16 + l15) * 128 + s * 32 + lg * 8]);
      b[t] = ldb8(&yRow[(size_t)(t * 16 + l15) * 128 + s * 32 + lg * 8]);
    }
#pragma unroll
    for (int i = 0; i < 4; ++i)
#pragma unroll
      for (int j = 0; j < 4; ++j) acc[i][j] = MFMA16(a[i], b[j], acc[i][j]);
  }
#pragma unroll
  for (int i = 0; i < 4; ++i)
#pragma unroll
    for (int r = 0; r < 4; ++r) {
      int o = o0 + i * 16 + lg * 4 + r;
      float bb = outb[o];
      __bf16* dst = y2b + ((size_t)n * CCH + o) * HW + px0;
#pragma unroll
      for (int j = 0; j < 4; ++j)
        dst[j * 16 + l15] = (__bf16)(acc[i][j][r] + bb);
    }
}

// ---------------------------------------------------------------------------
// c1 via MFMA (LDS-free): coef1 = relu(c1xB@xB + W2B@yTB + bias2), bf16 out
__global__ __launch_bounds__(256) void k_c1m(const __bf16* __restrict__ xB,
                                             const __bf16* __restrict__ yTB,
                                             const __bf16* __restrict__ c1xB,
                                             const __bf16* __restrict__ W2B,
                                             const float* __restrict__ bias2,
                                             __bf16* __restrict__ coef1) {
  const int n = blockIdx.y;
  const int px0 = blockIdx.x * 64;
  const int tid = threadIdx.x;
  const int w = tid >> 6, lane = tid & 63;
  const int l15 = lane & 15, lg = lane >> 4;
  const int o0 = w * 64;
  f32x4 acc[4][4];
#pragma unroll
  for (int i = 0; i < 4; ++i)
#pragma unroll
    for (int j = 0; j < 4; ++j) acc[i][j] = (f32x4){0, 0, 0, 0};

  const __bf16* xRow = xB + ((size_t)n * HW + px0) * 256;
  const __bf16* yRow = yTB + ((size_t)n * HW + px0) * 128;

#pragma unroll
  for (int s = 0; s < 8; ++s) {
    bf16x8 a[4], b[4];
#pragma unroll
    for (int t = 0; t < 4; ++t) {
      a[t] = ldb8(&c1xB[(size_t)(o0 + t * 16 + l15) * 256 + s * 32 + lg * 8]);
      b[t] = ldb8(&xRow[(size_t)(t * 16 + l15) * 256 + s * 32 + lg * 8]);
    }
#pragma unroll
    for (int i = 0; i < 4; ++i)
#pragma unroll
      for (int j = 0; j < 4; ++j) acc[i][j] = MFMA16(a[i], b[j], acc[i][j]);
  }
#pragma unroll
  for (int s = 0; s < 4; ++s) {
    bf16x8 a[4], b[4];
#pragma unroll
    for (int t = 0; t < 4; ++t) {
      a[t] = ldb8(&W2B[(size_t)(o0 + t * 16 + l15) * 128 + s * 32 + lg * 8]);
      b[t] = ldb8(&yRow[(size_t)(t * 16 + l15) * 128 + s * 32 + lg * 8]);
    }
#pragma unroll
    for (int i = 0; i < 4; ++i)
#pragma unroll
      for (int j = 0; j < 4; ++j) acc[i][j] = MFMA16(a[i], b[j], acc[i][j]);
  }
#pragma unroll
  for (int i = 0; i < 4; ++i)
#pragma unroll
    for (int r = 0; r < 4; ++r) {
      int o = o0 + i * 16 + lg * 4 + r;
      float bb = bias2[o];
      __bf16* dst = coef1 + ((size_t)n * CCH + o) * HW + px0;
#pragma unroll
      for (int j = 0; j < 4; ++j)
        dst[j * 16 + l15] = (__bf16)fmaxf(acc[i][j][r] + bb, 0.f);
    }
}

// ---------------------------------------------------------------------------
__global__ __launch_bounds__(256) void k_c2p(const __bf16* __restrict__ coef1,
                                             const float* __restrict__ w,
                                             float* __restrict__ part) {
  const int n = blockIdx.y;
  const int kc = blockIdx.z;
  const int p = blockIdx.x * 256 + threadIdx.x;
  const int px = p & 63, py = p >> 6;
  float acc[16];
#pragma unroll
  for (int o = 0; o < 16; ++o) acc[o] = 0.f;
  const __bf16* base = coef1 + (size_t)n * CCH * HW + (size_t)kc * 64 * HW;
  for (int c = 0; c < 64; ++c) {
    const __bf16* img = base + (size_t)c * HW;
    float v[9];
#pragma unroll
    for (int dy = -1; dy <= 1; ++dy)
#pragma unroll
      for (int dx = -1; dx <= 1; ++dx) {
        int yy = py + dy, xx = px + dx;
        bool ok = ((unsigned)yy < 64u) && ((unsigned)xx < 64u);
        v[(dy + 1) * 3 + dx + 1] = ok ? (float)img[yy * 64 + xx] : 0.f;
      }
    const int cg = kc * 64 + c;
#pragma unroll
    for (int o = 0; o < 16; ++o) {
      const float* wp = w + ((size_t)o * CCH + cg) * 9;
      float a = acc[o];
      a = fmaf(wp[0], v[0], a); a = fmaf(wp[1], v[1], a); a = fmaf(wp[2], v[2], a);
      a = fmaf(wp[3], v[3], a); a = fmaf(wp[4], v[4], a); a = fmaf(wp[5], v[5], a);
      a = fmaf(wp[6], v[6], a); a = fmaf(wp[7], v[7], a); a = fmaf(wp[8], v[8], a);
      acc[o] = a;
    }
  }
  float* dst = part + (((size_t)kc * 4 + n) * 16) * HW + p;
#pragma unroll
  for (int o = 0; o < 16; ++o) dst[(size_t)o * HW] = acc[o];
}

__global__ __launch_bounds__(256) void k_c2r(const float* __restrict__ part,
                                             const float* __restrict__ bias,
                                             float* __restrict__ c2o) {
  const int n = blockIdx.y;
  const int p = blockIdx.x * 256 + threadIdx.x;
#pragma unroll
  for (int o = 0; o < 16; ++o) {
    float s = bias[o];
#pragma unroll
    for (int kc = 0; kc < 4; ++kc)
      s += part[(((size_t)kc * 4 + n) * 16 + o) * HW + p];
    c2o[((size_t)n * 16 + o) * HW + p] = fmaxf(s, 0.f);
  }
}

// ---------------------------------------------------------------------------
__global__ __launch_bounds__(256) void k_c3(const float* __restrict__ c2o,
                                            const float* __restrict__ w,
                                            const float* __restrict__ bias,
                                            float* __restrict__ c3o) {
  const int n = blockIdx.y;
  const int p = blockIdx.x * 256 + threadIdx.x;
  const int px = p & 63, py = p >> 6;
  float acc[3] = {bias[0], bias[1], bias[2]};
  for (int c = 0; c < 16; ++c) {
    const float* img = c2o + ((size_t)n * 16 + c) * HW;
    float v[9];
#pragma unroll
    for (int dy = -1; dy <= 1; ++dy)
#pragma unroll
      for (int dx = -1; dx <= 1; ++dx) {
        int yy = py + dy, xx = px + dx;
        bool ok = ((unsigned)yy < 64u) && ((unsigned)xx < 64u);
        v[(dy + 1) * 3 + dx + 1] = ok ? img[yy * 64 + xx] : 0.f;
      }
#pragma unroll
    for (int o = 0; o < 3; ++o) {
      const float* wp = w + ((size_t)o * 16 + c) * 9;
      float a = acc[o];
      a = fmaf(wp[0], v[0], a); a = fmaf(wp[1], v[1], a); a = fmaf(wp[2], v[2], a);
      a = fmaf(wp[3], v[3], a); a = fmaf(wp[4], v[4], a); a = fmaf(wp[5], v[5], a);
      a = fmaf(wp[6], v[6], a); a = fmaf(wp[7], v[7], a); a = fmaf(wp[8], v[8], a);
      acc[o] = a;
    }
  }
#pragma unroll
  for (int o = 0; o < 3; ++o)
    c3o[((size_t)n * 3 + o) * HW + p] = fmaxf(acc[o], 0.f);
}

// ---------------------------------------------------------------------------
__global__ __launch_bounds__(256) void k_c4f(const float* __restrict__ c3o,
                                             const float* __restrict__ w4,
                                             const float* __restrict__ b4,
                                             const float* __restrict__ x,
                                             const __bf16* __restrict__ y2b,
                                             float* __restrict__ out0) {
  const int n = blockIdx.y;
  const int cc = blockIdx.z;
  const int p = blockIdx.x * 256 + threadIdx.x;
  const int px = p & 63, py = p >> 6;
  float coef = b4[0];
#pragma unroll
  for (int c = 0; c < 3; ++c) {
    const float* img = c3o + ((size_t)n * 3 + c) * HW;
#pragma unroll
    for (int dy = -1; dy <= 1; ++dy)
#pragma unroll
      for (int dx = -1; dx <= 1; ++dx) {
        int yy = py + dy, xx = px + dx;
        bool ok = ((unsigned)yy < 64u) && ((unsigned)xx < 64u);
        float v = ok ? img[yy * 64 + xx] : 0.f;
        coef = fmaf(w4[c * 9 + (dy + 1) * 3 + dx + 1], v, coef);
      }
  }
  const size_t base = ((size_t)n * CCH + cc * 64) * HW + p;
#pragma unroll 8
  for (int c = 0; c < 64; ++c) {
    size_t a = base + (size_t)c * HW;
    out0[a] = x[a] + coef * (float)y2b[a];
  }
}

// ---------------------------------------------------------------------------
extern "C" void kernel_launch(void* const* d_in, const int* in_sizes, int n_in,
                              void* d_out, int out_size, void* d_ws, size_t ws_size,
                              hipStream_t stream) {
  (void)in_sizes; (void)n_in; (void)out_size; (void)ws_size;
  const float* x     = (const float*)d_in[0];
  const float* x_ref = (const float*)d_in[1];
  const float* g_w   = (const float*)d_in[2];
  const float* g_b   = (const float*)d_in[3];
  const float* th_w  = (const float*)d_in[4];
  const float* th_b  = (const float*)d_in[5];
  const float* ph_w  = (const float*)d_in[6];
  const float* ph_b  = (const float*)d_in[7];
  const float* out_w = (const float*)d_in[8];
  const float* out_b = (const float*)d_in[9];
  const float* c1_w  = (const float*)d_in[10];
  const float* c1_b  = (const float*)d_in[11];
  const float* c2_w  = (const float*)d_in[12];
  const float* c2_b  = (const float*)d_in[13];
  const float* c3_w  = (const float*)d_in[14];
  const float* c3_b  = (const float*)d_in[15];
  const float* c4_w  = (const float*)d_in[16];
  const float* c4_b  = (const float*)d_in[17];

  float* ws = (float*)d_ws;
  __bf16* xB     = (__bf16*)(ws + 0);
  __bf16* yTB    = (__bf16*)(ws + 2097152);
  __bf16* thB    = (__bf16*)(ws + 3145728);
  __bf16* phB    = (__bf16*)(ws + 4194304);
  __bf16* gB2    = (__bf16*)(ws + 5242880);
  __bf16* coef1B = (__bf16*)(ws + 3145728);  // aliases thB+phB (dead after attnB)
  __bf16* y2b    = (__bf16*)(ws + 6291456);
  float* c2p     = ws + 8388608;
  float* c2o     = ws + 9437184;
  float* c3o     = ws + 9699328;
  __bf16* c1xB   = (__bf16*)(ws + 9748480);
  __bf16* W2B    = (__bf16*)(ws + 9781248);
  __bf16* outwB  = (__bf16*)(ws + 9797632);
  float* bias2   = ws + 9814016;
  float* partRS  = ws + 9814272;   // 65536 floats
  float* yTpart  = ws + 9879808;   // 8,388,608 floats (4 kq partials)

  float* out0 = (float*)d_out;
  float* P    = out0 + 4194304;

  dim3 blk(256);
  k_projT<<<dim3(64, 4), blk, 0, stream>>>(x, th_w, th_b, thB, xB);
  k_projPG<<<dim3(64, 4), blk, 0, stream>>>(x_ref, ph_w, g_w, ph_b, g_b, phB, gB2);
  k_prep<<<dim3(512), blk, 0, stream>>>(c1_w, c1_b, out_w, out_b, c1xB, W2B, outwB, bias2);
  k_attnA<<<dim3(64, 4, 4), blk, 0, stream>>>(thB, phB, partRS);
  k_attnB<<<dim3(64, 4, 4), blk, 0, stream>>>(thB, phB, gB2, partRS, P, yTpart);
  k_yred<<<dim3(256, 4), blk, 0, stream>>>(yTpart, yTB);
  k_outm<<<dim3(64, 4), blk, 0, stream>>>(yTB, outwB, out_b, y2b);
  k_c1m<<<dim3(64, 4), blk, 0, stream>>>(xB, yTB, c1xB, W2B, bias2, coef1B);
  k_c2p<<<dim3(16, 4, 4), blk, 0, stream>>>(coef1B, c2_w, c2p);
  k_c2r<<<dim3(16, 4), blk, 0, stream>>>(c2p, c2_b, c2o);
  k_c3<<<dim3(16, 4), blk, 0, stream>>>(c2o, c3_w, c3_b, c3o);
  k_c4f<<<dim3(16, 4, 4), blk, 0, stream>>>(c3o, c4_w, c4_b, x, y2b, out0);
}